// Round 18
// baseline (4051.455 us; speedup 1.0000x reference)
//
#include <hip/hip_runtime.h>
#include <math.h>

#define N_NODES   20000
#define N_PAD2    20096   // 157 * 128 (fourier row-group granularity)
#define N_EDGES   320000
#define N_GRAPHS  64
#define IN_FEAT   64
#define HIDDEN    256
#define GRID_F    4
#define NLAYERS   3
#define NEG_SLOPE 0.01f

#define KF 2048   // fourier K = HIDDEN * 8 (cos/sin x k=1..4, interleaved)
#define KL4 256   // line K padded: 64 feats x 4 slots [x,x^2,x^3,x^4]; deg-0 -> bias
#define NB_SCAN 79  // ceil(20000/256)
#define NRG  157    // fourier row groups of 128
#define NBLK (NRG * 4)  // 628 fourier blocks
#define NLBLK 1256  // kan_line: 314 rowgroups(64) x 4 colblocks(64) = 8*157

typedef _Float16 f16x8 __attribute__((ext_vector_type(8)));
typedef _Float16 f16x2 __attribute__((ext_vector_type(2)));
typedef float    f32x4 __attribute__((ext_vector_type(4)));
typedef float    f32x16 __attribute__((ext_vector_type(16)));
typedef unsigned short u16x4 __attribute__((ext_vector_type(4)));

// Non-draining barrier: LDS ops ordered (lgkmcnt 0), global loads stay in
// flight (NO vmcnt drain, unlike __syncthreads). sched_barrier(0) on both
// sides pins code motion (rule #18 + read-hoist-past-raw-barrier hazard).
#define LBAR() do { \
    asm volatile("s_waitcnt lgkmcnt(0)" ::: "memory"); \
    __builtin_amdgcn_sched_barrier(0); \
    __builtin_amdgcn_s_barrier(); \
    __builtin_amdgcn_sched_barrier(0); \
} while (0)

// u16 fixed-point phase: q = frac(v/2pi) * 65536. Additive mod 2^16 == mod 1 rev.
__device__ __forceinline__ unsigned short phase16(float v) {
    float r = v * 0.15915494309189535f;
    r -= floorf(r);
    return (unsigned short)((unsigned)(r * 65536.f + 0.5f) & 0xFFFFu);
}

// ---------- weight transposes ----------
// fp16 Bt[l][o][kk], kk = i*8 + g*2 + t  (g -> harmonic k=g+1 ; t=0:cos,1:sin)
__global__ void transpose_fourier_f16(const float* __restrict__ fc, _Float16* __restrict__ Bt) {
    int idx = blockIdx.x * 256 + threadIdx.x;      // 3*256*2048 total
    int kk  = idx & 2047;
    int rest = idx >> 11;
    int o = rest & 255;
    int l = rest >> 8;
    int i = kk >> 3, f = kk & 7, g = f >> 1, t = f & 1;
    Bt[idx] = (_Float16)fc[(((size_t)(l * 2 + t) * HIDDEN + o) * HIDDEN + i) * GRID_F + g];
}

// kan_line weights -> split f16 hi/lo, layout Wt[o][kk'], kk' = i*4 + (d-1), d=1..4
__global__ void transpose_line4(const float* __restrict__ wl, _Float16* __restrict__ Wth,
                                _Float16* __restrict__ Wtl) {
    int idx = blockIdx.x * 256 + threadIdx.x;      // 256*256
    int o = idx >> 8, kk = idx & 255;
    int i = kk >> 2, d = (kk & 3) + 1;
    float wv = wl[(o * IN_FEAT + i) * 5 + d];
    _Float16 h = (_Float16)wv;
    Wth[idx] = h;
    Wtl[idx] = (_Float16)(wv - (float)h);
}

// bias[o] = sum_i W[o][i][0]  (degree-0 terms, x^0 = 1)
__global__ void line_bias(const float* __restrict__ wl, float* __restrict__ biasv) {
    int o = threadIdx.x;   // 256
    float s = 0.f;
    for (int i = 0; i < IN_FEAT; ++i) s += wl[(o * IN_FEAT + i) * 5];
    biasv[o] = s;
}

// ---------- CSR build (group edges by dst) ----------
__global__ void count_deg(const int* __restrict__ dst, int* __restrict__ counts) {
    int e = blockIdx.x * 256 + threadIdx.x;
    if (e < N_EDGES) atomicAdd(&counts[dst[e]], 1);
}

__global__ void block_sums(const int* __restrict__ counts, int* __restrict__ bsum) {
    int i = blockIdx.x * 256 + threadIdx.x;
    int v = (i < N_NODES) ? counts[i] : 0;
    #pragma unroll
    for (int o = 32; o > 0; o >>= 1) v += __shfl_down(v, o, 64);
    __shared__ int ws[4];
    if ((threadIdx.x & 63) == 0) ws[threadIdx.x >> 6] = v;
    __syncthreads();
    if (threadIdx.x == 0) bsum[blockIdx.x] = ws[0] + ws[1] + ws[2] + ws[3];
}

__global__ void scan_mid(const int* __restrict__ bsum, int* __restrict__ bofs,
                         int* __restrict__ row_start) {
    __shared__ int buf[128];
    int t = threadIdx.x;
    int v = (t < NB_SCAN) ? bsum[t] : 0;
    buf[t] = v;
    __syncthreads();
    for (int d = 1; d < 128; d <<= 1) {
        int x = (t >= d) ? buf[t - d] : 0;
        __syncthreads();
        buf[t] += x;
        __syncthreads();
    }
    if (t < NB_SCAN) bofs[t] = buf[t] - v;          // exclusive
    if (t == NB_SCAN - 1) row_start[N_NODES] = buf[t];
}

__global__ void scan_blocks(const int* __restrict__ counts, const int* __restrict__ bofs,
                            int* __restrict__ row_start) {
    int i = blockIdx.x * 256 + threadIdx.x;
    int val = (i < N_NODES) ? counts[i] : 0;
    int lane = threadIdx.x & 63, wid = threadIdx.x >> 6;
    int v = val;
    #pragma unroll
    for (int d = 1; d < 64; d <<= 1) {
        int t = __shfl_up(v, d, 64);
        if (lane >= d) v += t;
    }
    __shared__ int ws[4];
    if (lane == 63) ws[wid] = v;
    __syncthreads();
    int wofs = 0;
    for (int j = 0; j < wid; ++j) wofs += ws[j];
    if (i < N_NODES) row_start[i] = bofs[blockIdx.x] + wofs + v - val;  // exclusive
}

__global__ void fill_csr(const int* __restrict__ src, const int* __restrict__ dst,
                         const int* __restrict__ row_start, int* __restrict__ cursor,
                         int* __restrict__ ssrc) {
    int e = blockIdx.x * 256 + threadIdx.x;
    if (e < N_EDGES) {
        int d = dst[e];
        int pos = row_start[d] + atomicAdd(&cursor[d], 1);
        ssrc[pos] = src[e];
    }
}

// ---------- aggregation v16: u16-phase gather (half bytes, EXACT mod-1 sum) ----------
__global__ __launch_bounds__(256)
void aggregate(const unsigned short* __restrict__ hq, const int* __restrict__ row_start,
               const int* __restrict__ ssrc, unsigned* __restrict__ cs) {
    const int node = blockIdx.x * 4 + (threadIdx.x >> 6);
    const int lane = threadIdx.x & 63;
    const int b = row_start[node], e = row_start[node + 1];
    u16x4 a0 = {0, 0, 0, 0}, a1 = {0, 0, 0, 0}, a2 = {0, 0, 0, 0}, a3 = {0, 0, 0, 0};
    int j = b;
    for (; j + 3 < e; j += 4) {
        int s0 = ssrc[j], s1 = ssrc[j + 1], s2 = ssrc[j + 2], s3 = ssrc[j + 3];
        a0 += *(const u16x4*)&hq[(size_t)s0 * HIDDEN + lane * 4];
        a1 += *(const u16x4*)&hq[(size_t)s1 * HIDDEN + lane * 4];
        a2 += *(const u16x4*)&hq[(size_t)s2 * HIDDEN + lane * 4];
        a3 += *(const u16x4*)&hq[(size_t)s3 * HIDDEN + lane * 4];
    }
    for (; j < e; ++j) {
        int s0 = ssrc[j];
        a0 += *(const u16x4*)&hq[(size_t)s0 * HIDDEN + lane * 4];
    }
    u16x4 s = (a0 + a1) + (a2 + a3);      // wrapping adds == exact mod 1 rev
    unsigned csv[4];
    #pragma unroll
    for (int k = 0; k < 4; ++k) {
        float r = (float)s[k] * (1.f / 65536.f);   // revolutions, [0,1)
        _Float16 ch = (_Float16)__builtin_amdgcn_cosf(r);
        _Float16 sh = (_Float16)__builtin_amdgcn_sinf(r);
        union { f16x2 z; unsigned u; } p;
        p.z = (f16x2){ch, sh};
        csv[k] = p.u;
    }
    *(uint4*)&cs[(size_t)node * HIDDEN + lane * 4] = make_uint4(csv[0], csv[1], csv[2], csv[3]);
}

// ---------- kan_line: split-f16 MFMA (v10, verified) + u16 phase write ----------
__device__ __forceinline__ void makepow(float xa, float xb, f16x8& hi, f16x8& lo) {
    float p0 = xa, p1 = xa * xa;
    float p2 = p1 * xa, p3 = p1 * p1;
    float q0 = xb, q1 = xb * xb;
    float q2 = q1 * xb, q3 = q1 * q1;
    float pp[8] = {p0, p1, p2, p3, q0, q1, q2, q3};
    #pragma unroll
    for (int j = 0; j < 8; ++j) {
        _Float16 h = (_Float16)pp[j];
        hi[j] = h;
        lo[j] = (_Float16)(pp[j] - (float)h);
    }
}

__global__ __launch_bounds__(256)
void kan_line_mfma(const float* __restrict__ x, const _Float16* __restrict__ Wth,
                   const _Float16* __restrict__ Wtl, const float* __restrict__ biasv,
                   float* __restrict__ out, unsigned short* __restrict__ hqo) {
    __shared__ float    As[64][64];       // x, XOR-swizzled cols (16KB)
    __shared__ _Float16 Bsh[64][136];     // W hi, one 128-kk group (17.4KB)
    __shared__ _Float16 Bsl[64][136];     // W lo

    const int t = threadIdx.x;
    const int w = t >> 6, l = t & 63, ln = l & 15, quad = l >> 4;
    const int wr = w >> 1, wc = w & 1;

    const int g   = blockIdx.x;                 // 1256 = 8*157
    const int bid = (g & 7) * 157 + (g >> 3);   // bijective XCD swizzle
    const int Mbase = (bid >> 2) * 64;
    const int col0  = (bid & 3) * 64;

    // ---- stage x rows (clamped: input buffer ends exactly at row 20000) ----
    #pragma unroll
    for (int r = 0; r < 4; ++r) {
        int idx = r * 256 + t;
        int row = idx >> 4, p = idx & 15;
        int grow = Mbase + row;
        if (grow > N_NODES - 1) grow = N_NODES - 1;
        f32x4 v = *(const f32x4*)&x[(size_t)grow * IN_FEAT + p * 4];
        *(f32x4*)&As[row][(p * 4) ^ ((row & 7) << 2)] = v;
    }
    // ---- stage B group 0 (kk 0..127) ----
    const _Float16* WthB = Wth + (size_t)col0 * KL4;
    const _Float16* WtlB = Wtl + (size_t)col0 * KL4;
    #pragma unroll
    for (int r = 0; r < 4; ++r) {
        int idx = r * 256 + t;
        int c = idx >> 4, p = idx & 15;
        *(f16x8*)&Bsh[c][p * 8] = *(const f16x8*)&WthB[(size_t)c * KL4 + p * 8];
        *(f16x8*)&Bsl[c][p * 8] = *(const f16x8*)&WtlB[(size_t)c * KL4 + p * 8];
    }
    // issue group-1 global loads early (latency hides under group-0 compute)
    f16x8 pbh[4], pbl[4];
    #pragma unroll
    for (int r = 0; r < 4; ++r) {
        int idx = r * 256 + t;
        int c = idx >> 4, p = idx & 15;
        pbh[r] = *(const f16x8*)&WthB[(size_t)c * KL4 + 128 + p * 8];
        pbl[r] = *(const f16x8*)&WtlB[(size_t)c * KL4 + 128 + p * 8];
    }
    __syncthreads();

    f32x4 acc[2][2];
    #pragma unroll
    for (int rt = 0; rt < 2; ++rt)
        #pragma unroll
        for (int ct = 0; ct < 2; ++ct)
            acc[rt][ct] = (f32x4){0.f, 0.f, 0.f, 0.f};

    const int lr0 = wr * 32 + ln;            // row for rt=0 (rt=1: +16, same &7)
    const int xsw = (lr0 & 7) << 2;

    #pragma unroll
    for (int half = 0; half < 2; ++half) {
        #pragma unroll
        for (int kcl = 0; kcl < 4; ++kcl) {
            const int kc = half * 4 + kcl;
            const int f0 = kc * 8 + quad * 2;
            float x00 = As[lr0     ][f0 ^ xsw];
            float x01 = As[lr0     ][(f0 + 1) ^ xsw];
            float x10 = As[lr0 + 16][f0 ^ xsw];
            float x11 = As[lr0 + 16][(f0 + 1) ^ xsw];
            f16x8 ah0, al0, ah1, al1;
            makepow(x00, x01, ah0, al0);
            makepow(x10, x11, ah1, al1);
            #pragma unroll
            for (int ct = 0; ct < 2; ++ct) {
                const int bc = wc * 32 + ct * 16 + ln;
                f16x8 bh = *(const f16x8*)&Bsh[bc][kcl * 32 + quad * 8];
                f16x8 bl = *(const f16x8*)&Bsl[bc][kcl * 32 + quad * 8];
                acc[0][ct] = __builtin_amdgcn_mfma_f32_16x16x32_f16(ah0, bh, acc[0][ct], 0, 0, 0);
                acc[0][ct] = __builtin_amdgcn_mfma_f32_16x16x32_f16(al0, bh, acc[0][ct], 0, 0, 0);
                acc[0][ct] = __builtin_amdgcn_mfma_f32_16x16x32_f16(ah0, bl, acc[0][ct], 0, 0, 0);
                acc[1][ct] = __builtin_amdgcn_mfma_f32_16x16x32_f16(ah1, bh, acc[1][ct], 0, 0, 0);
                acc[1][ct] = __builtin_amdgcn_mfma_f32_16x16x32_f16(al1, bh, acc[1][ct], 0, 0, 0);
                acc[1][ct] = __builtin_amdgcn_mfma_f32_16x16x32_f16(ah1, bl, acc[1][ct], 0, 0, 0);
            }
        }
        if (half == 0) {
            __syncthreads();
            #pragma unroll
            for (int r = 0; r < 4; ++r) {
                int idx = r * 256 + t;
                int c = idx >> 4, p = idx & 15;
                *(f16x8*)&Bsh[c][p * 8] = pbh[r];
                *(f16x8*)&Bsl[c][p * 8] = pbl[r];
            }
            __syncthreads();
        }
    }

    // epilogue: + degree-0 bias; C layout col=ln, row=quad*4+reg
    #pragma unroll
    for (int rt = 0; rt < 2; ++rt) {
        const int row0 = Mbase + wr * 32 + rt * 16 + quad * 4;
        #pragma unroll
        for (int ct = 0; ct < 2; ++ct) {
            const int col = col0 + wc * 32 + ct * 16 + ln;
            const float bv = biasv[col];
            #pragma unroll
            for (int r = 0; r < 4; ++r) {
                const int row = row0 + r;
                if (row < N_NODES) {
                    float vv = acc[rt][ct][r] + bv;
                    out[(size_t)row * HIDDEN + col] = vv;
                    hqo[(size_t)row * HIDDEN + col] = phase16(vv);
                }
            }
        }
    }
}

// ---------- fourier layer, v20: v19 + non-draining barriers + depth-2 prefetch ----------
// v16..v19 converged at 46-49us with ALL pipes <=25% busy -> the invariant is
// the 16 __syncthreads phases: hipcc emits s_waitcnt vmcnt(0) before s_barrier
// (guide §5), draining the prefetch every phase; in-flight window = compute
// phase only. v20: (1) LBAR() = lgkmcnt(0)+sched_barrier+s_barrier+sched_barrier
// -- LDS ordered, vmcnt NOT drained; (2) two register prefetch sets, set
// consumed at kg was issued at kg-2 -> counted vmcnt wait (other set stays in
// flight across the barrier). Math/tiling/epilogue identical to v19 (passed).
// (R1's raw-barrier "failure" was re-attributed to the agg aliasing race.)
__device__ __forceinline__ f16x8 expand4(unsigned csu) {
    union { unsigned u; f16x2 z; } w; w.u = csu;
    f16x2 z1 = w.z;
    f16x2 cc = {z1[0], z1[0]};
    f16x2 ms = {(_Float16)(-z1[1]), z1[1]};
    f16x2 z2 = z1 * cc + (f16x2){z1[1], z1[0]} * ms;
    f16x2 z3 = z2 * cc + (f16x2){z2[1], z2[0]} * ms;
    f16x2 z4 = z3 * cc + (f16x2){z3[1], z3[0]} * ms;
    union { f16x8 v; f16x2 p[4]; } u;
    u.p[0] = z1; u.p[1] = z2; u.p[2] = z3; u.p[3] = z4;
    return u.v;
}

__global__ __launch_bounds__(256)
void fourier_mfma(const unsigned* __restrict__ cs, float* hio,
                  const _Float16* __restrict__ Bt, unsigned short* __restrict__ hqo) {
    __shared__ _Float16 Bs[2][64][140];   // 64 cols x 128 K halves, pad to 140
    __shared__ unsigned As[2][128][17];   // 128 rows x 16 cs-pairs, pad to 17

    const int t  = threadIdx.x;
    const int w  = t >> 6;            // 4 waves
    const int l  = t & 63;
    const int m  = l & 31;            // row/col within 32-group
    const int hi = l >> 5;            // k-half select
    const int rh = w & 1;             // row half (0: rows 0-63, 1: 64-127)
    const int cq = w >> 1;            // col quarter (0: cols 0-31, 1: 32-63)

    // bijective XCD swizzle, 628 = 8*78 + 4 (m204 form)
    const int g   = blockIdx.x;
    const int xcd = g & 7, ii = g >> 3;
    const int bid = (xcd < 4 ? xcd * 79 : 316 + (xcd - 4) * 78) + ii;
    const int Mbase = (bid >> 2) * 128;
    const int col0  = (bid & 3) * 64;

    // staging thread mapping (256 threads, coalesced)
    const int sc = t >> 4, sp = t & 15;   // B: piece sp, cols sc+16i, i=0..3
    const int sr = t >> 2, sq = t & 3;    // As: uint4 sq, rows sr+64i, i=0..1
    const _Float16* bg = Bt + (size_t)(col0 + sc) * KF + sp * 8;
    const unsigned* ag = cs + (size_t)(Mbase + sr) * HIDDEN + sq * 4;

    f32x16 acc[2];
    #pragma unroll
    for (int rg = 0; rg < 2; ++rg)
        #pragma unroll
        for (int r = 0; r < 16; ++r) acc[rg][r] = 0.f;

    // ---- stage group 0 directly ----
    {
        f16x8 tb[4];
        uint4 ta[2];
        #pragma unroll
        for (int i = 0; i < 4; ++i) tb[i] = *(const f16x8*)(bg + (size_t)(16 * i) * KF);
        #pragma unroll
        for (int i = 0; i < 2; ++i) ta[i] = *(const uint4*)(ag + (size_t)(64 * i) * HIDDEN);
        #pragma unroll
        for (int i = 0; i < 4; ++i) *(f16x8*)&Bs[0][sc + 16 * i][sp * 8] = tb[i];
        #pragma unroll
        for (int i = 0; i < 2; ++i) {
            As[0][sr + 64 * i][sq * 4 + 0] = ta[i].x;
            As[0][sr + 64 * i][sq * 4 + 1] = ta[i].y;
            As[0][sr + 64 * i][sq * 4 + 2] = ta[i].z;
            As[0][sr + 64 * i][sq * 4 + 3] = ta[i].w;
        }
    }
    // ---- depth-2 prefetch: set[1] <- group1, set[0] <- group2 ----
    f16x8 pb[2][4];
    uint4 pa[2][2];
    #pragma unroll
    for (int i = 0; i < 4; ++i) pb[1][i] = *(const f16x8*)(bg + (size_t)(16 * i) * KF + 128);
    #pragma unroll
    for (int i = 0; i < 2; ++i) pa[1][i] = *(const uint4*)(ag + (size_t)(64 * i) * HIDDEN + 16);
    #pragma unroll
    for (int i = 0; i < 4; ++i) pb[0][i] = *(const f16x8*)(bg + (size_t)(16 * i) * KF + 256);
    #pragma unroll
    for (int i = 0; i < 2; ++i) pa[0][i] = *(const uint4*)(ag + (size_t)(64 * i) * HIDDEN + 32);
    LBAR();

    const int ar0 = rh * 64 + m;      // A row, rg=0 (rg=1: +32)
    const int bc  = cq * 32 + m;      // B col

    for (int kg = 0; kg < 16; ++kg) {
        const int b = kg & 1;
        // 8 K16-steps from buf b: step covers feats {2*step, 2*step+1}
        #pragma unroll
        for (int step = 0; step < 8; ++step) {
            unsigned cv0 = As[b][ar0     ][step * 2 + hi];
            unsigned cv1 = As[b][ar0 + 32][step * 2 + hi];
            f16x8 bb = *(const f16x8*)&Bs[b][bc][step * 16 + hi * 8];
            f16x8 a0 = expand4(cv0);
            f16x8 a1 = expand4(cv1);
            acc[0] = __builtin_amdgcn_mfma_f32_32x32x16_f16(a0, bb, acc[0], 0, 0, 0);
            acc[1] = __builtin_amdgcn_mfma_f32_32x32x16_f16(a1, bb, acc[1], 0, 0, 0);
        }
        if (kg < 15) {
            const int s  = (kg + 1) & 1;   // set holding group kg+1 (issued kg-2)
            const int nb = b ^ 1;
            // ds_write waits (counted) only on set s; other set stays in flight
            #pragma unroll
            for (int i = 0; i < 4; ++i) *(f16x8*)&Bs[nb][sc + 16 * i][sp * 8] = pb[s][i];
            #pragma unroll
            for (int i = 0; i < 2; ++i) {
                As[nb][sr + 64 * i][sq * 4 + 0] = pa[s][i].x;
                As[nb][sr + 64 * i][sq * 4 + 1] = pa[s][i].y;
                As[nb][sr + 64 * i][sq * 4 + 2] = pa[s][i].z;
                As[nb][sr + 64 * i][sq * 4 + 3] = pa[s][i].w;
            }
            if (kg + 3 <= 15) {   // reload set s with group kg+3
                #pragma unroll
                for (int i = 0; i < 4; ++i)
                    pb[s][i] = *(const f16x8*)(bg + (size_t)(16 * i) * KF + (kg + 3) * 128);
                #pragma unroll
                for (int i = 0; i < 2; ++i)
                    pa[s][i] = *(const uint4*)(ag + (size_t)(64 * i) * HIDDEN + (kg + 3) * 16);
            }
        }
        LBAR();
    }

    // epilogue: residual + leaky relu.
    // 32x32 C layout (HW-verified m74/m101, validated by v18/v19 passes):
    // col = col0+cq*32+m, row = base + (r&3) + 8*(r>>2) + 4*hi.
    // In-place on hio safe: each (row,col) read once by its owner then written.
    #pragma unroll
    for (int rg = 0; rg < 2; ++rg) {
        const int rbase = Mbase + rh * 64 + rg * 32 + 4 * hi;
        const int col = col0 + cq * 32 + m;
        #pragma unroll
        for (int r = 0; r < 16; ++r) {
            const int row = rbase + (r & 3) + 8 * (r >> 2);
            if (row < N_NODES) {
                float v = acc[rg][r] + hio[(size_t)row * HIDDEN + col];
                v = v > 0.f ? v : NEG_SLOPE * v;
                hio[(size_t)row * HIDDEN + col] = v;
                hqo[(size_t)row * HIDDEN + col] = phase16(v);
            }
        }
    }
}

// ---------- per-graph pooling: gid is SORTED -> segmented register accumulation ----
__global__ void graph_bounds(const int* __restrict__ gid, int* __restrict__ gstart) {
    int g = threadIdx.x;
    if (g < N_GRAPHS) {
        int lo = 0, hi = N_NODES;
        while (lo < hi) { int mid = (lo + hi) >> 1; if (gid[mid] < g) lo = mid + 1; else hi = mid; }
        gstart[g] = lo;
    } else if (g == N_GRAPHS) {
        gstart[g] = N_NODES;
    }
}

__global__ __launch_bounds__(256)
void pool_seg(const float* __restrict__ h, const int* __restrict__ gid,
              float* __restrict__ pooled) {
    const int c = threadIdx.x;
    const int s = blockIdx.x * 128;
    const int e = min(s + 128, N_NODES);
    float acc = 0.f;
    int g = gid[s];
    for (int n = s; n < e; ++n) {
        int gn = gid[n];
        if (gn != g) {
            atomicAdd(&pooled[g * HIDDEN + c], acc);
            acc = 0.f;
            g = gn;
        }
        acc += h[(size_t)n * HIDDEN + c];
    }
    atomicAdd(&pooled[g * HIDDEN + c], acc);
}

// ---------- readout ----------
__global__ void readout(const float* __restrict__ pooled, const int* __restrict__ gstart,
                        const float* __restrict__ wout, const float* __restrict__ bout,
                        float* __restrict__ out) {
    int g = blockIdx.x, t = threadIdx.x;
    float cnt = fmaxf((float)(gstart[g + 1] - gstart[g]), 1.f);
    float y = pooled[g * HIDDEN + t] / cnt;
    float term = wout[t * 2 + 0] + wout[t * 2 + 1] * y;
    #pragma unroll
    for (int o = 32; o > 0; o >>= 1) term += __shfl_down(term, o, 64);
    __shared__ float wsum[4];
    if ((t & 63) == 0) wsum[t >> 6] = term;
    __syncthreads();
    if (t == 0) {
        float s = wsum[0] + wsum[1] + wsum[2] + wsum[3] + bout[0];
        out[g] = 1.f / (1.f + expf(-s));
    }
}

extern "C" void kernel_launch(void* const* d_in, const int* in_sizes, int n_in,
                              void* d_out, int out_size, void* d_ws, size_t ws_size,
                              hipStream_t stream) {
    const float* h_in  = (const float*)d_in[0];
    const int*   src   = (const int*)d_in[1];
    const int*   dst   = (const int*)d_in[2];
    const int*   gid   = (const int*)d_in[3];
    const float* wline = (const float*)d_in[4];
    const float* fcoef = (const float*)d_in[5];
    const float* wout  = (const float*)d_in[6];
    const float* bout  = (const float*)d_in[7];
    float* out = (float*)d_out;

    char* ws = (char*)d_ws;
    size_t off = 0;
    auto alloc = [&](size_t bytes) {
        size_t o = off;
        off += (bytes + 255) & ~size_t(255);
        return o;
    };
    float*          hbuf      = (float*)(ws + alloc((size_t)N_PAD2 * HIDDEN * 4));  // h f32
    unsigned short* hqbuf     = (unsigned short*)(ws + alloc((size_t)N_PAD2 * HIDDEN * 2)); // u16 phase
    unsigned*       csbuf     = (unsigned*)(ws + alloc((size_t)N_PAD2 * HIDDEN * 4)); // cs pairs
    _Float16*       BtF16     = (_Float16*)(ws + alloc((size_t)NLAYERS * KF * HIDDEN * 2));
    _Float16*       Wth       = (_Float16*)(ws + alloc((size_t)HIDDEN * KL4 * 2));
    _Float16*       Wtl       = (_Float16*)(ws + alloc((size_t)HIDDEN * KL4 * 2));
    float*          biasv     = (float*)(ws + alloc((size_t)HIDDEN * 4));
    int*            row_start = (int*)(ws + alloc((size_t)(N_NODES + 1) * 4));
    int*            counts    = (int*)(ws + alloc((size_t)N_NODES * 4));
    int*            cursor    = (int*)(ws + alloc((size_t)N_NODES * 4));
    int*            ssrc      = (int*)(ws + alloc((size_t)N_EDGES * 4));
    int*            bsum      = (int*)(ws + alloc((size_t)128 * 4));
    int*            bofs      = (int*)(ws + alloc((size_t)128 * 4));
    int*            gstart    = (int*)(ws + alloc((size_t)(N_GRAPHS + 1) * 4));
    float*          pooled    = (float*)(ws + alloc((size_t)N_GRAPHS * HIDDEN * 4));

    hipMemsetAsync(counts, 0, (size_t)N_NODES * 4, stream);
    hipMemsetAsync(cursor, 0, (size_t)N_NODES * 4, stream);
    hipMemsetAsync(pooled, 0, (size_t)N_GRAPHS * HIDDEN * 4, stream);
    // pad rows (20000..20095) of csbuf: zeros -> z1=(0,0) -> zero A fragments
    hipMemsetAsync(csbuf + (size_t)N_NODES * HIDDEN, 0,
                   (size_t)(N_PAD2 - N_NODES) * HIDDEN * 4, stream);

    transpose_fourier_f16<<<6144, 256, 0, stream>>>(fcoef, BtF16);
    transpose_line4<<<256, 256, 0, stream>>>(wline, Wth, Wtl);
    line_bias<<<1, 256, 0, stream>>>(wline, biasv);
    count_deg<<<(N_EDGES + 255) / 256, 256, 0, stream>>>(dst, counts);
    block_sums<<<NB_SCAN, 256, 0, stream>>>(counts, bsum);
    scan_mid<<<1, 128, 0, stream>>>(bsum, bofs, row_start);
    scan_blocks<<<NB_SCAN, 256, 0, stream>>>(counts, bofs, row_start);
    fill_csr<<<(N_EDGES + 255) / 256, 256, 0, stream>>>(src, dst, row_start, cursor, ssrc);
    graph_bounds<<<1, 128, 0, stream>>>(gid, gstart);

    kan_line_mfma<<<NLBLK, 256, 0, stream>>>(h_in, Wth, Wtl, biasv, hbuf, hqbuf);

    for (int l = 0; l < NLAYERS; ++l) {
        aggregate<<<N_NODES / 4, 256, 0, stream>>>(hqbuf, row_start, ssrc, csbuf);
        fourier_mfma<<<NBLK, 256, 0, stream>>>(csbuf, hbuf,
                                               BtF16 + (size_t)l * KF * HIDDEN, hqbuf);
    }

    pool_seg<<<(N_NODES + 127) / 128, 256, 0, stream>>>(hbuf, gid, pooled);
    readout<<<N_GRAPHS, 256, 0, stream>>>(pooled, gstart, wout, bout, out);
}

// Round 19
// 392.565 us; speedup vs baseline: 10.3205x; 10.3205x over previous
//
#include <hip/hip_runtime.h>
#include <math.h>

#define N_NODES   20000
#define N_PAD2    20096   // 157 * 128 (fourier row-group granularity)
#define N_EDGES   320000
#define N_GRAPHS  64
#define IN_FEAT   64
#define HIDDEN    256
#define GRID_F    4
#define NLAYERS   3
#define NEG_SLOPE 0.01f

#define KF 2048   // fourier K = HIDDEN * 8 (cos/sin x k=1..4, interleaved)
#define KL4 256   // line K padded: 64 feats x 4 slots [x,x^2,x^3,x^4]; deg-0 -> bias
#define NB_SCAN 79  // ceil(20000/256)
#define NRG  157    // fourier row groups of 128
#define NBLK (NRG * 4)  // 628 fourier blocks
#define NLBLK 1256  // kan_line: 314 rowgroups(64) x 4 colblocks(64) = 8*157

typedef _Float16 f16x8 __attribute__((ext_vector_type(8)));
typedef _Float16 f16x2 __attribute__((ext_vector_type(2)));
typedef float    f32x4 __attribute__((ext_vector_type(4)));
typedef unsigned short u16x4 __attribute__((ext_vector_type(4)));

// u16 fixed-point phase: q = frac(v/2pi) * 65536. Additive mod 2^16 == mod 1 rev.
__device__ __forceinline__ unsigned short phase16(float v) {
    float r = v * 0.15915494309189535f;
    r -= floorf(r);
    return (unsigned short)((unsigned)(r * 65536.f + 0.5f) & 0xFFFFu);
}

// ---------- weight transposes ----------
// fp16 Bt[l][o][kk], kk = i*8 + g*2 + t  (g -> harmonic k=g+1 ; t=0:cos,1:sin)
__global__ void transpose_fourier_f16(const float* __restrict__ fc, _Float16* __restrict__ Bt) {
    int idx = blockIdx.x * 256 + threadIdx.x;      // 3*256*2048 total
    int kk  = idx & 2047;
    int rest = idx >> 11;
    int o = rest & 255;
    int l = rest >> 8;
    int i = kk >> 3, f = kk & 7, g = f >> 1, t = f & 1;
    Bt[idx] = (_Float16)fc[(((size_t)(l * 2 + t) * HIDDEN + o) * HIDDEN + i) * GRID_F + g];
}

// kan_line weights -> split f16 hi/lo, layout Wt[o][kk'], kk' = i*4 + (d-1), d=1..4
__global__ void transpose_line4(const float* __restrict__ wl, _Float16* __restrict__ Wth,
                                _Float16* __restrict__ Wtl) {
    int idx = blockIdx.x * 256 + threadIdx.x;      // 256*256
    int o = idx >> 8, kk = idx & 255;
    int i = kk >> 2, d = (kk & 3) + 1;
    float wv = wl[(o * IN_FEAT + i) * 5 + d];
    _Float16 h = (_Float16)wv;
    Wth[idx] = h;
    Wtl[idx] = (_Float16)(wv - (float)h);
}

// bias[o] = sum_i W[o][i][0]  (degree-0 terms, x^0 = 1)
__global__ void line_bias(const float* __restrict__ wl, float* __restrict__ biasv) {
    int o = threadIdx.x;   // 256
    float s = 0.f;
    for (int i = 0; i < IN_FEAT; ++i) s += wl[(o * IN_FEAT + i) * 5];
    biasv[o] = s;
}

// ---------- CSR build (group edges by dst) ----------
__global__ void count_deg(const int* __restrict__ dst, int* __restrict__ counts) {
    int e = blockIdx.x * 256 + threadIdx.x;
    if (e < N_EDGES) atomicAdd(&counts[dst[e]], 1);
}

__global__ void block_sums(const int* __restrict__ counts, int* __restrict__ bsum) {
    int i = blockIdx.x * 256 + threadIdx.x;
    int v = (i < N_NODES) ? counts[i] : 0;
    #pragma unroll
    for (int o = 32; o > 0; o >>= 1) v += __shfl_down(v, o, 64);
    __shared__ int ws[4];
    if ((threadIdx.x & 63) == 0) ws[threadIdx.x >> 6] = v;
    __syncthreads();
    if (threadIdx.x == 0) bsum[blockIdx.x] = ws[0] + ws[1] + ws[2] + ws[3];
}

__global__ void scan_mid(const int* __restrict__ bsum, int* __restrict__ bofs,
                         int* __restrict__ row_start) {
    __shared__ int buf[128];
    int t = threadIdx.x;
    int v = (t < NB_SCAN) ? bsum[t] : 0;
    buf[t] = v;
    __syncthreads();
    for (int d = 1; d < 128; d <<= 1) {
        int x = (t >= d) ? buf[t - d] : 0;
        __syncthreads();
        buf[t] += x;
        __syncthreads();
    }
    if (t < NB_SCAN) bofs[t] = buf[t] - v;          // exclusive
    if (t == NB_SCAN - 1) row_start[N_NODES] = buf[t];
}

__global__ void scan_blocks(const int* __restrict__ counts, const int* __restrict__ bofs,
                            int* __restrict__ row_start) {
    int i = blockIdx.x * 256 + threadIdx.x;
    int val = (i < N_NODES) ? counts[i] : 0;
    int lane = threadIdx.x & 63, wid = threadIdx.x >> 6;
    int v = val;
    #pragma unroll
    for (int d = 1; d < 64; d <<= 1) {
        int t = __shfl_up(v, d, 64);
        if (lane >= d) v += t;
    }
    __shared__ int ws[4];
    if (lane == 63) ws[wid] = v;
    __syncthreads();
    int wofs = 0;
    for (int j = 0; j < wid; ++j) wofs += ws[j];
    if (i < N_NODES) row_start[i] = bofs[blockIdx.x] + wofs + v - val;  // exclusive
}

__global__ void fill_csr(const int* __restrict__ src, const int* __restrict__ dst,
                         const int* __restrict__ row_start, int* __restrict__ cursor,
                         int* __restrict__ ssrc) {
    int e = blockIdx.x * 256 + threadIdx.x;
    if (e < N_EDGES) {
        int d = dst[e];
        int pos = row_start[d] + atomicAdd(&cursor[d], 1);
        ssrc[pos] = src[e];
    }
}

// ---------- aggregation v16: u16-phase gather (half bytes, EXACT mod-1 sum) ----------
__global__ __launch_bounds__(256)
void aggregate(const unsigned short* __restrict__ hq, const int* __restrict__ row_start,
               const int* __restrict__ ssrc, unsigned* __restrict__ cs) {
    const int node = blockIdx.x * 4 + (threadIdx.x >> 6);
    const int lane = threadIdx.x & 63;
    const int b = row_start[node], e = row_start[node + 1];
    u16x4 a0 = {0, 0, 0, 0}, a1 = {0, 0, 0, 0}, a2 = {0, 0, 0, 0}, a3 = {0, 0, 0, 0};
    int j = b;
    for (; j + 3 < e; j += 4) {
        int s0 = ssrc[j], s1 = ssrc[j + 1], s2 = ssrc[j + 2], s3 = ssrc[j + 3];
        a0 += *(const u16x4*)&hq[(size_t)s0 * HIDDEN + lane * 4];
        a1 += *(const u16x4*)&hq[(size_t)s1 * HIDDEN + lane * 4];
        a2 += *(const u16x4*)&hq[(size_t)s2 * HIDDEN + lane * 4];
        a3 += *(const u16x4*)&hq[(size_t)s3 * HIDDEN + lane * 4];
    }
    for (; j < e; ++j) {
        int s0 = ssrc[j];
        a0 += *(const u16x4*)&hq[(size_t)s0 * HIDDEN + lane * 4];
    }
    u16x4 s = (a0 + a1) + (a2 + a3);      // wrapping adds == exact mod 1 rev
    unsigned csv[4];
    #pragma unroll
    for (int k = 0; k < 4; ++k) {
        float r = (float)s[k] * (1.f / 65536.f);   // revolutions, [0,1)
        _Float16 ch = (_Float16)__builtin_amdgcn_cosf(r);
        _Float16 sh = (_Float16)__builtin_amdgcn_sinf(r);
        union { f16x2 z; unsigned u; } p;
        p.z = (f16x2){ch, sh};
        csv[k] = p.u;
    }
    *(uint4*)&cs[(size_t)node * HIDDEN + lane * 4] = make_uint4(csv[0], csv[1], csv[2], csv[3]);
}

// ---------- kan_line: split-f16 MFMA (v10, verified) + u16 phase write ----------
__device__ __forceinline__ void makepow(float xa, float xb, f16x8& hi, f16x8& lo) {
    float p0 = xa, p1 = xa * xa;
    float p2 = p1 * xa, p3 = p1 * p1;
    float q0 = xb, q1 = xb * xb;
    float q2 = q1 * xb, q3 = q1 * q1;
    float pp[8] = {p0, p1, p2, p3, q0, q1, q2, q3};
    #pragma unroll
    for (int j = 0; j < 8; ++j) {
        _Float16 h = (_Float16)pp[j];
        hi[j] = h;
        lo[j] = (_Float16)(pp[j] - (float)h);
    }
}

__global__ __launch_bounds__(256)
void kan_line_mfma(const float* __restrict__ x, const _Float16* __restrict__ Wth,
                   const _Float16* __restrict__ Wtl, const float* __restrict__ biasv,
                   float* __restrict__ out, unsigned short* __restrict__ hqo) {
    __shared__ float    As[64][64];       // x, XOR-swizzled cols (16KB)
    __shared__ _Float16 Bsh[64][136];     // W hi, one 128-kk group (17.4KB)
    __shared__ _Float16 Bsl[64][136];     // W lo

    const int t = threadIdx.x;
    const int w = t >> 6, l = t & 63, ln = l & 15, quad = l >> 4;
    const int wr = w >> 1, wc = w & 1;

    const int g   = blockIdx.x;                 // 1256 = 8*157
    const int bid = (g & 7) * 157 + (g >> 3);   // bijective XCD swizzle
    const int Mbase = (bid >> 2) * 64;
    const int col0  = (bid & 3) * 64;

    // ---- stage x rows (clamped: input buffer ends exactly at row 20000) ----
    #pragma unroll
    for (int r = 0; r < 4; ++r) {
        int idx = r * 256 + t;
        int row = idx >> 4, p = idx & 15;
        int grow = Mbase + row;
        if (grow > N_NODES - 1) grow = N_NODES - 1;
        f32x4 v = *(const f32x4*)&x[(size_t)grow * IN_FEAT + p * 4];
        *(f32x4*)&As[row][(p * 4) ^ ((row & 7) << 2)] = v;
    }
    // ---- stage B group 0 (kk 0..127) ----
    const _Float16* WthB = Wth + (size_t)col0 * KL4;
    const _Float16* WtlB = Wtl + (size_t)col0 * KL4;
    #pragma unroll
    for (int r = 0; r < 4; ++r) {
        int idx = r * 256 + t;
        int c = idx >> 4, p = idx & 15;
        *(f16x8*)&Bsh[c][p * 8] = *(const f16x8*)&WthB[(size_t)c * KL4 + p * 8];
        *(f16x8*)&Bsl[c][p * 8] = *(const f16x8*)&WtlB[(size_t)c * KL4 + p * 8];
    }
    // issue group-1 global loads early (latency hides under group-0 compute)
    f16x8 pbh[4], pbl[4];
    #pragma unroll
    for (int r = 0; r < 4; ++r) {
        int idx = r * 256 + t;
        int c = idx >> 4, p = idx & 15;
        pbh[r] = *(const f16x8*)&WthB[(size_t)c * KL4 + 128 + p * 8];
        pbl[r] = *(const f16x8*)&WtlB[(size_t)c * KL4 + 128 + p * 8];
    }
    __syncthreads();

    f32x4 acc[2][2];
    #pragma unroll
    for (int rt = 0; rt < 2; ++rt)
        #pragma unroll
        for (int ct = 0; ct < 2; ++ct)
            acc[rt][ct] = (f32x4){0.f, 0.f, 0.f, 0.f};

    const int lr0 = wr * 32 + ln;            // row for rt=0 (rt=1: +16, same &7)
    const int xsw = (lr0 & 7) << 2;

    #pragma unroll
    for (int half = 0; half < 2; ++half) {
        #pragma unroll
        for (int kcl = 0; kcl < 4; ++kcl) {
            const int kc = half * 4 + kcl;
            const int f0 = kc * 8 + quad * 2;
            float x00 = As[lr0     ][f0 ^ xsw];
            float x01 = As[lr0     ][(f0 + 1) ^ xsw];
            float x10 = As[lr0 + 16][f0 ^ xsw];
            float x11 = As[lr0 + 16][(f0 + 1) ^ xsw];
            f16x8 ah0, al0, ah1, al1;
            makepow(x00, x01, ah0, al0);
            makepow(x10, x11, ah1, al1);
            #pragma unroll
            for (int ct = 0; ct < 2; ++ct) {
                const int bc = wc * 32 + ct * 16 + ln;
                f16x8 bh = *(const f16x8*)&Bsh[bc][kcl * 32 + quad * 8];
                f16x8 bl = *(const f16x8*)&Bsl[bc][kcl * 32 + quad * 8];
                acc[0][ct] = __builtin_amdgcn_mfma_f32_16x16x32_f16(ah0, bh, acc[0][ct], 0, 0, 0);
                acc[0][ct] = __builtin_amdgcn_mfma_f32_16x16x32_f16(al0, bh, acc[0][ct], 0, 0, 0);
                acc[0][ct] = __builtin_amdgcn_mfma_f32_16x16x32_f16(ah0, bl, acc[0][ct], 0, 0, 0);
                acc[1][ct] = __builtin_amdgcn_mfma_f32_16x16x32_f16(ah1, bh, acc[1][ct], 0, 0, 0);
                acc[1][ct] = __builtin_amdgcn_mfma_f32_16x16x32_f16(al1, bh, acc[1][ct], 0, 0, 0);
                acc[1][ct] = __builtin_amdgcn_mfma_f32_16x16x32_f16(ah1, bl, acc[1][ct], 0, 0, 0);
            }
        }
        if (half == 0) {
            __syncthreads();
            #pragma unroll
            for (int r = 0; r < 4; ++r) {
                int idx = r * 256 + t;
                int c = idx >> 4, p = idx & 15;
                *(f16x8*)&Bsh[c][p * 8] = pbh[r];
                *(f16x8*)&Bsl[c][p * 8] = pbl[r];
            }
            __syncthreads();
        }
    }

    // epilogue: + degree-0 bias; C layout col=ln, row=quad*4+reg
    #pragma unroll
    for (int rt = 0; rt < 2; ++rt) {
        const int row0 = Mbase + wr * 32 + rt * 16 + quad * 4;
        #pragma unroll
        for (int ct = 0; ct < 2; ++ct) {
            const int col = col0 + wc * 32 + ct * 16 + ln;
            const float bv = biasv[col];
            #pragma unroll
            for (int r = 0; r < 4; ++r) {
                const int row = row0 + r;
                if (row < N_NODES) {
                    float vv = acc[rt][ct][r] + bv;
                    out[(size_t)row * HIDDEN + col] = vv;
                    hqo[(size_t)row * HIDDEN + col] = phase16(vv);
                }
            }
        }
    }
}

// ---------- fourier layer, v16 (best measured: 46.4us): cs-pairs + 1 barrier/kg ----------
// Converged structure: v16 46.4 / v17 48.8 / v18 59.2 / v19 48.7 / v20 (hand
// pipeline) catastrophic. All pipes <=25% busy across variants -> barrier/
// latency structural at HIP source level; compiler-scheduled __syncthreads
// double-buffer is the local optimum (m97/m141 class).
__device__ __forceinline__ f16x8 expand4(unsigned csu) {
    union { unsigned u; f16x2 z; } w; w.u = csu;
    f16x2 z1 = w.z;
    f16x2 cc = {z1[0], z1[0]};
    f16x2 ms = {(_Float16)(-z1[1]), z1[1]};
    f16x2 z2 = z1 * cc + (f16x2){z1[1], z1[0]} * ms;
    f16x2 z3 = z2 * cc + (f16x2){z2[1], z2[0]} * ms;
    f16x2 z4 = z3 * cc + (f16x2){z3[1], z3[0]} * ms;
    union { f16x8 v; f16x2 p[4]; } u;
    u.p[0] = z1; u.p[1] = z2; u.p[2] = z3; u.p[3] = z4;
    return u.v;
}

__global__ __launch_bounds__(256)
void fourier_mfma(const unsigned* __restrict__ cs, float* hio,
                  const _Float16* __restrict__ Bt, unsigned short* __restrict__ hqo) {
    __shared__ _Float16 Bs[2][64][140];   // 64 cols x 128 K halves, pad to 140
    __shared__ unsigned As[2][128][17];   // 128 rows x 16 cs-pairs, pad to 17

    const int t    = threadIdx.x;
    const int w    = t >> 6;
    const int l    = t & 63;
    const int ln   = l & 15;
    const int quad = l >> 4;

    // bijective XCD swizzle, 628 = 8*78 + 4 (m204 form)
    const int g   = blockIdx.x;
    const int xcd = g & 7, ii = g >> 3;
    const int bid = (xcd < 4 ? xcd * 79 : 316 + (xcd - 4) * 78) + ii;
    const int Mbase = (bid >> 2) * 128;
    const int col0  = (bid & 3) * 64;

    // staging thread mapping (coalesced 64B-line loads)
    const int sc = t >> 4, sp = t & 15;   // B: col sc(+16k), 16B piece sp
    const int sr = t >> 2, sq = t & 3;    // cs: row sr(+64k), 16B piece sq
    const _Float16* bg0 = Bt + (size_t)(col0 + sc) * KF + sp * 8;
    const _Float16* bg1 = bg0 + (size_t)16 * KF;
    const _Float16* bg2 = bg0 + (size_t)32 * KF;
    const _Float16* bg3 = bg0 + (size_t)48 * KF;
    const unsigned* ag0 = cs + (size_t)(Mbase + sr) * HIDDEN + sq * 4;
    const unsigned* ag1 = ag0 + (size_t)64 * HIDDEN;

    f32x4 acc[2][4];
    #pragma unroll
    for (int rt = 0; rt < 2; ++rt)
        #pragma unroll
        for (int ct = 0; ct < 4; ++ct)
            acc[rt][ct] = (f32x4){0.f, 0.f, 0.f, 0.f};

    f16x8 sb0, sb1, sb2, sb3;
    uint4 sa0, sa1;

    // ---- stage group 0 ----
    sb0 = *(const f16x8*)(bg0);
    sb1 = *(const f16x8*)(bg1);
    sb2 = *(const f16x8*)(bg2);
    sb3 = *(const f16x8*)(bg3);
    sa0 = *(const uint4*)(ag0);
    sa1 = *(const uint4*)(ag1);
    *(f16x8*)&Bs[0][sc     ][sp * 8] = sb0;
    *(f16x8*)&Bs[0][sc + 16][sp * 8] = sb1;
    *(f16x8*)&Bs[0][sc + 32][sp * 8] = sb2;
    *(f16x8*)&Bs[0][sc + 48][sp * 8] = sb3;
    As[0][sr     ][sq * 4 + 0] = sa0.x;
    As[0][sr     ][sq * 4 + 1] = sa0.y;
    As[0][sr     ][sq * 4 + 2] = sa0.z;
    As[0][sr     ][sq * 4 + 3] = sa0.w;
    As[0][sr + 64][sq * 4 + 0] = sa1.x;
    As[0][sr + 64][sq * 4 + 1] = sa1.y;
    As[0][sr + 64][sq * 4 + 2] = sa1.z;
    As[0][sr + 64][sq * 4 + 3] = sa1.w;
    __syncthreads();

    const int lr0 = w * 32 + ln;        // local row, rt=0 (rt=1 adds 16)

    for (int kg = 0; kg < 16; ++kg) {
        const int b = kg & 1;
        // issue next group's global loads (latency hides under compute)
        if (kg < 15) {
            sb0 = *(const f16x8*)(bg0 + (kg + 1) * 128);
            sb1 = *(const f16x8*)(bg1 + (kg + 1) * 128);
            sb2 = *(const f16x8*)(bg2 + (kg + 1) * 128);
            sb3 = *(const f16x8*)(bg3 + (kg + 1) * 128);
            sa0 = *(const uint4*)(ag0 + (kg + 1) * 16);
            sa1 = *(const uint4*)(ag1 + (kg + 1) * 16);
        }
        // compute 4 k-chunks from buf b
        #pragma unroll
        for (int kc = 0; kc < 4; ++kc) {
            unsigned cv0 = As[b][lr0     ][kc * 4 + quad];
            unsigned cv1 = As[b][lr0 + 16][kc * 4 + quad];
            f16x8 b0 = *(const f16x8*)&Bs[b][ln     ][kc * 32 + quad * 8];
            f16x8 b1 = *(const f16x8*)&Bs[b][ln + 16][kc * 32 + quad * 8];
            f16x8 b2 = *(const f16x8*)&Bs[b][ln + 32][kc * 32 + quad * 8];
            f16x8 b3 = *(const f16x8*)&Bs[b][ln + 48][kc * 32 + quad * 8];
            f16x8 a0 = expand4(cv0);
            f16x8 a1 = expand4(cv1);
            acc[0][0] = __builtin_amdgcn_mfma_f32_16x16x32_f16(a0, b0, acc[0][0], 0, 0, 0);
            acc[0][1] = __builtin_amdgcn_mfma_f32_16x16x32_f16(a0, b1, acc[0][1], 0, 0, 0);
            acc[0][2] = __builtin_amdgcn_mfma_f32_16x16x32_f16(a0, b2, acc[0][2], 0, 0, 0);
            acc[0][3] = __builtin_amdgcn_mfma_f32_16x16x32_f16(a0, b3, acc[0][3], 0, 0, 0);
            acc[1][0] = __builtin_amdgcn_mfma_f32_16x16x32_f16(a1, b0, acc[1][0], 0, 0, 0);
            acc[1][1] = __builtin_amdgcn_mfma_f32_16x16x32_f16(a1, b1, acc[1][1], 0, 0, 0);
            acc[1][2] = __builtin_amdgcn_mfma_f32_16x16x32_f16(a1, b2, acc[1][2], 0, 0, 0);
            acc[1][3] = __builtin_amdgcn_mfma_f32_16x16x32_f16(a1, b3, acc[1][3], 0, 0, 0);
        }
        // write next buffer (no hazard with this iteration's reads: different
        // buffer; cross-iteration hazards guarded by the barrier below)
        if (kg < 15) {
            const int nb = b ^ 1;
            *(f16x8*)&Bs[nb][sc     ][sp * 8] = sb0;
            *(f16x8*)&Bs[nb][sc + 16][sp * 8] = sb1;
            *(f16x8*)&Bs[nb][sc + 32][sp * 8] = sb2;
            *(f16x8*)&Bs[nb][sc + 48][sp * 8] = sb3;
            As[nb][sr     ][sq * 4 + 0] = sa0.x;
            As[nb][sr     ][sq * 4 + 1] = sa0.y;
            As[nb][sr     ][sq * 4 + 2] = sa0.z;
            As[nb][sr     ][sq * 4 + 3] = sa0.w;
            As[nb][sr + 64][sq * 4 + 0] = sa1.x;
            As[nb][sr + 64][sq * 4 + 1] = sa1.y;
            As[nb][sr + 64][sq * 4 + 2] = sa1.z;
            As[nb][sr + 64][sq * 4 + 3] = sa1.w;
        }
        __syncthreads();
    }

    // epilogue: residual + leaky relu (C layout: col=ln, row=quad*4+reg).
    // In-place on hio is safe: each (row,col) read once by its owning thread,
    // immediately before that thread writes it. hq phase mirror written too.
    #pragma unroll
    for (int rt = 0; rt < 2; ++rt) {
        const int row0 = Mbase + w * 32 + rt * 16 + quad * 4;
        #pragma unroll
        for (int ct = 0; ct < 4; ++ct) {
            const int col = col0 + ct * 16 + ln;
            #pragma unroll
            for (int r = 0; r < 4; ++r) {
                const int row = row0 + r;
                if (row < N_NODES) {
                    float v = acc[rt][ct][r] + hio[(size_t)row * HIDDEN + col];
                    v = v > 0.f ? v : NEG_SLOPE * v;
                    hio[(size_t)row * HIDDEN + col] = v;
                    hqo[(size_t)row * HIDDEN + col] = phase16(v);
                }
            }
        }
    }
}

// ---------- per-graph pooling: gid is SORTED -> segmented register accumulation ----
__global__ void graph_bounds(const int* __restrict__ gid, int* __restrict__ gstart) {
    int g = threadIdx.x;
    if (g < N_GRAPHS) {
        int lo = 0, hi = N_NODES;
        while (lo < hi) { int mid = (lo + hi) >> 1; if (gid[mid] < g) lo = mid + 1; else hi = mid; }
        gstart[g] = lo;
    } else if (g == N_GRAPHS) {
        gstart[g] = N_NODES;
    }
}

__global__ __launch_bounds__(256)
void pool_seg(const float* __restrict__ h, const int* __restrict__ gid,
              float* __restrict__ pooled) {
    const int c = threadIdx.x;
    const int s = blockIdx.x * 128;
    const int e = min(s + 128, N_NODES);
    float acc = 0.f;
    int g = gid[s];
    for (int n = s; n < e; ++n) {
        int gn = gid[n];
        if (gn != g) {
            atomicAdd(&pooled[g * HIDDEN + c], acc);
            acc = 0.f;
            g = gn;
        }
        acc += h[(size_t)n * HIDDEN + c];
    }
    atomicAdd(&pooled[g * HIDDEN + c], acc);
}

// ---------- readout ----------
__global__ void readout(const float* __restrict__ pooled, const int* __restrict__ gstart,
                        const float* __restrict__ wout, const float* __restrict__ bout,
                        float* __restrict__ out) {
    int g = blockIdx.x, t = threadIdx.x;
    float cnt = fmaxf((float)(gstart[g + 1] - gstart[g]), 1.f);
    float y = pooled[g * HIDDEN + t] / cnt;
    float term = wout[t * 2 + 0] + wout[t * 2 + 1] * y;
    #pragma unroll
    for (int o = 32; o > 0; o >>= 1) term += __shfl_down(term, o, 64);
    __shared__ float wsum[4];
    if ((t & 63) == 0) wsum[t >> 6] = term;
    __syncthreads();
    if (t == 0) {
        float s = wsum[0] + wsum[1] + wsum[2] + wsum[3] + bout[0];
        out[g] = 1.f / (1.f + expf(-s));
    }
}

extern "C" void kernel_launch(void* const* d_in, const int* in_sizes, int n_in,
                              void* d_out, int out_size, void* d_ws, size_t ws_size,
                              hipStream_t stream) {
    const float* h_in  = (const float*)d_in[0];
    const int*   src   = (const int*)d_in[1];
    const int*   dst   = (const int*)d_in[2];
    const int*   gid   = (const int*)d_in[3];
    const float* wline = (const float*)d_in[4];
    const float* fcoef = (const float*)d_in[5];
    const float* wout  = (const float*)d_in[6];
    const float* bout  = (const float*)d_in[7];
    float* out = (float*)d_out;

    char* ws = (char*)d_ws;
    size_t off = 0;
    auto alloc = [&](size_t bytes) {
        size_t o = off;
        off += (bytes + 255) & ~size_t(255);
        return o;
    };
    float*          hbuf      = (float*)(ws + alloc((size_t)N_PAD2 * HIDDEN * 4));  // h f32
    unsigned short* hqbuf     = (unsigned short*)(ws + alloc((size_t)N_PAD2 * HIDDEN * 2)); // u16 phase
    unsigned*       csbuf     = (unsigned*)(ws + alloc((size_t)N_PAD2 * HIDDEN * 4)); // cs pairs
    _Float16*       BtF16     = (_Float16*)(ws + alloc((size_t)NLAYERS * KF * HIDDEN * 2));
    _Float16*       Wth       = (_Float16*)(ws + alloc((size_t)HIDDEN * KL4 * 2));
    _Float16*       Wtl       = (_Float16*)(ws + alloc((size_t)HIDDEN * KL4 * 2));
    float*          biasv     = (float*)(ws + alloc((size_t)HIDDEN * 4));
    int*            row_start = (int*)(ws + alloc((size_t)(N_NODES + 1) * 4));
    int*            counts    = (int*)(ws + alloc((size_t)N_NODES * 4));
    int*            cursor    = (int*)(ws + alloc((size_t)N_NODES * 4));
    int*            ssrc      = (int*)(ws + alloc((size_t)N_EDGES * 4));
    int*            bsum      = (int*)(ws + alloc((size_t)128 * 4));
    int*            bofs      = (int*)(ws + alloc((size_t)128 * 4));
    int*            gstart    = (int*)(ws + alloc((size_t)(N_GRAPHS + 1) * 4));
    float*          pooled    = (float*)(ws + alloc((size_t)N_GRAPHS * HIDDEN * 4));

    hipMemsetAsync(counts, 0, (size_t)N_NODES * 4, stream);
    hipMemsetAsync(cursor, 0, (size_t)N_NODES * 4, stream);
    hipMemsetAsync(pooled, 0, (size_t)N_GRAPHS * HIDDEN * 4, stream);
    // pad rows (20000..20095) of csbuf: zeros -> z1=(0,0) -> zero A fragments
    hipMemsetAsync(csbuf + (size_t)N_NODES * HIDDEN, 0,
                   (size_t)(N_PAD2 - N_NODES) * HIDDEN * 4, stream);

    transpose_fourier_f16<<<6144, 256, 0, stream>>>(fcoef, BtF16);
    transpose_line4<<<256, 256, 0, stream>>>(wline, Wth, Wtl);
    line_bias<<<1, 256, 0, stream>>>(wline, biasv);
    count_deg<<<(N_EDGES + 255) / 256, 256, 0, stream>>>(dst, counts);
    block_sums<<<NB_SCAN, 256, 0, stream>>>(counts, bsum);
    scan_mid<<<1, 128, 0, stream>>>(bsum, bofs, row_start);
    scan_blocks<<<NB_SCAN, 256, 0, stream>>>(counts, bofs, row_start);
    fill_csr<<<(N_EDGES + 255) / 256, 256, 0, stream>>>(src, dst, row_start, cursor, ssrc);
    graph_bounds<<<1, 128, 0, stream>>>(gid, gstart);

    kan_line_mfma<<<NLBLK, 256, 0, stream>>>(h_in, Wth, Wtl, biasv, hbuf, hqbuf);

    for (int l = 0; l < NLAYERS; ++l) {
        aggregate<<<N_NODES / 4, 256, 0, stream>>>(hqbuf, row_start, ssrc, csbuf);
        fourier_mfma<<<NBLK, 256, 0, stream>>>(csbuf, hbuf,
                                               BtF16 + (size_t)l * KF * HIDDEN, hqbuf);
    }

    pool_seg<<<(N_NODES + 127) / 128, 256, 0, stream>>>(hbuf, gid, pooled);
    readout<<<N_GRAPHS, 256, 0, stream>>>(pooled, gstart, wout, bout, out);
}